// Round 1
// baseline (662.332 us; speedup 1.0000x reference)
//
#include <hip/hip_runtime.h>
#include <stdint.h>

#define E_    8
#define D_    2048
#define I_    1408
#define TWOI_ 2816
#define N_    8192
#define BM    128
#define MAXTILES 72
#define MPAD  9216
#define MAXST 40
#define NCT1  11

typedef __bf16 bf16x8 __attribute__((ext_vector_type(8)));
typedef float  floatx4 __attribute__((ext_vector_type(4)));

// ---- meta layout (int offsets into ws) ----
#define M_CNT   0    // [8]
#define M_CUR   8    // [8]
#define M_PB    16   // padbase[8]
#define M_NT    24   // ntiles (128-row tiles, used by gemm2)
#define M_RTE   32   // rt_expert[72]
#define M_RTR   104  // rt_row0[72]
#define M_RTV   176  // rt_nvalid[72]
#define M_NST   248  // n super-tiles (256-row, gemm1)
#define M_STE   256  // st_expert[40]
#define M_STR   296  // st_row0[40]
#define M_STV   336  // st_nvalid[40]

// ---- ws byte offsets ----
#define OFF_PERM  4096ULL
#define OFF_WPAD  40960ULL
#define OFF_APAD  81920ULL
#define OFF_HPAD  37830656ULL
#define OFF_GU    63782912ULL
#define OFF_DN    156057600ULL
#define WS_NEED   202194944ULL

__device__ inline void gload16(const void* g, void* lds) {
  __builtin_amdgcn_global_load_lds(
      (__attribute__((address_space(1))) void*)g,
      (__attribute__((address_space(3))) void*)lds, 16, 0, 0);
}

__device__ inline unsigned short f2bf(float f) {
  unsigned int u = __builtin_bit_cast(unsigned int, f);
  u += 0x7fffu + ((u >> 16) & 1u);   // RNE; inputs finite
  return (unsigned short)(u >> 16);
}

// ---------------- routing (ballot-based: 8 atomics/wave, not 64) ----------------
__global__ void k_hist(const int* __restrict__ ids, int* meta) {
  int i = blockIdx.x * 256 + threadIdx.x;   // N_ divisible by 256: all lanes live
  int e = ids[i];
  int lane = threadIdx.x & 63;
  for (int ex = 0; ex < E_; ++ex) {
    unsigned long long m = __ballot(e == ex);
    if (lane == 0 && m) atomicAdd(&meta[M_CNT + ex], __popcll(m));
  }
}

__global__ void k_meta(int* meta) {
  if (threadIdx.x != 0) return;
  int padr = 0, tiles = 0;
  for (int e = 0; e < E_; ++e) {
    meta[M_PB + e] = padr;
    int c = meta[M_CNT + e];
    int nt = (c + BM - 1) / BM;
    for (int t = 0; t < nt; ++t) {
      meta[M_RTE + tiles] = e;
      meta[M_RTR + tiles] = padr + t * BM;
      int v = c - t * BM; if (v > BM) v = BM;
      meta[M_RTV + tiles] = v;
      tiles++;
    }
    padr += nt * BM;
  }
  meta[M_NT] = tiles;
  // 256-row super-tiles for gemm1 (pairs of 128-tiles; padding layout unchanged)
  int nst = 0;
  for (int e = 0; e < E_; ++e) {
    int c = meta[M_CNT + e];
    int pb = meta[M_PB + e];
    for (int off = 0; off < c; off += 256) {
      meta[M_STE + nst] = e;
      meta[M_STR + nst] = pb + off;
      int v = c - off; if (v > 256) v = 256;
      meta[M_STV + nst] = v;
      nst++;
    }
  }
  meta[M_NST] = nst;
}

__global__ void k_scatter(const int* __restrict__ ids, const float* __restrict__ w,
                          int* meta, int* perm, float* wpad) {
  int i = blockIdx.x * 256 + threadIdx.x;
  int e = ids[i];
  float wv = w[i];
  int lane = threadIdx.x & 63;
  for (int ex = 0; ex < E_; ++ex) {
    unsigned long long m = __ballot(e == ex);
    if (!m) continue;                       // m is wave-uniform
    int base = 0;
    if (lane == 0) base = atomicAdd(&meta[M_CUR + ex], __popcll(m));
    base = __shfl(base, 0);
    if (e == ex) {
      int r = meta[M_PB + ex] + base + __popcll(m & ((1ULL << lane) - 1ULL));
      perm[r] = i;
      wpad[r] = wv;
    }
  }
}

// -------------- gather tokens -> bf16 (permuted, padded) --------------
__global__ void k_gather(const float* __restrict__ tokens, const int* __restrict__ perm,
                         unsigned short* __restrict__ apad) {
  int r = blockIdx.x;
  int t = perm[r];
  if (t < 0) return;  // pad row: leave as-is
  const float4* src = (const float4*)(tokens + (size_t)t * D_);
  uint4* dst = (uint4*)(apad + (size_t)r * D_);
  int i = threadIdx.x;  // 256 threads x 8 floats = 2048
  float4 a = src[i * 2], b = src[i * 2 + 1];
  union { unsigned short s[8]; uint4 v; } pk;
  pk.s[0] = f2bf(a.x); pk.s[1] = f2bf(a.y); pk.s[2] = f2bf(a.z); pk.s[3] = f2bf(a.w);
  pk.s[4] = f2bf(b.x); pk.s[5] = f2bf(b.y); pk.s[6] = f2bf(b.z); pk.s[7] = f2bf(b.w);
  dst[i] = pk.v;
}

// -------------- fp32 -> bf16 weight convert --------------
__global__ void k_cvt(const float* __restrict__ src, unsigned short* __restrict__ dst, int n8) {
  int i = blockIdx.x * 256 + threadIdx.x;  // each handles 8 elements
  if (i >= n8) return;
  const float4* s4 = (const float4*)src;
  float4 a = s4[i * 2], b = s4[i * 2 + 1];
  union { unsigned short s[8]; uint4 v; } pk;
  pk.s[0] = f2bf(a.x); pk.s[1] = f2bf(a.y); pk.s[2] = f2bf(a.z); pk.s[3] = f2bf(a.w);
  pk.s[4] = f2bf(b.x); pk.s[5] = f2bf(b.y); pk.s[6] = f2bf(b.z); pk.s[7] = f2bf(b.w);
  ((uint4*)dst)[i] = pk.v;
}

// =====================================================================
// GEMM1: fc1 = A @ gate_up^T, fused SwiGLU -> h (bf16)
// 8-phase counted-vmcnt schedule (T3+T4), BM=256 super-tiles, BN=128g+128u,
// BK=64, 512 thr / 8 waves, wave tile 128x64, LDS 128KiB dbuf,
// T2 chunk-XOR swizzle (pre-swizzled global src for global_load_lds),
// T5 setprio around MFMA clusters, runtime-bijective XCD chunk swizzle (T1).
// Waits are vmcnt(6) at phase-0 end and vmcnt(8) at phase-3 end — never 0.
// =====================================================================

#define RD_A(h, s)                                                            \
  {                                                                           \
    const char* baseA_ = (const char*)&Abuf[s][h][0];                         \
    _Pragma("unroll") for (int mf = 0; mf < 4; ++mf) {                        \
      af[mf][0] = *(const bf16x8*)(baseA_ + rbA + mf * 2048 + swz0);          \
      af[mf][1] = *(const bf16x8*)(baseA_ + rbA + mf * 2048 + swz1);          \
    }                                                                         \
  }

#define RD_B(h, s)                                                            \
  {                                                                           \
    const char* baseB_ = (const char*)&Bbuf[s][h][0];                         \
    _Pragma("unroll") for (int nf = 0; nf < 2; ++nf) {                        \
      bq[nf][0] = *(const bf16x8*)(baseB_ + cbB + nf * 2048 + swz0);          \
      bq[nf][1] = *(const bf16x8*)(baseB_ + cbB + nf * 2048 + swz1);          \
    }                                                                         \
  }

#define MFMA_PH(qi)                                                           \
  __builtin_amdgcn_s_setprio(1);                                              \
  _Pragma("unroll") for (int mf = 0; mf < 4; ++mf) {                          \
    _Pragma("unroll") for (int nf = 0; nf < 2; ++nf) {                        \
      acc[qi][mf][nf] = __builtin_amdgcn_mfma_f32_16x16x32_bf16(              \
          af[mf][0], bq[nf][0], acc[qi][mf][nf], 0, 0, 0);                    \
      acc[qi][mf][nf] = __builtin_amdgcn_mfma_f32_16x16x32_bf16(              \
          af[mf][1], bq[nf][1], acc[qi][mf][nf], 0, 0, 0);                    \
    }                                                                         \
  }                                                                           \
  __builtin_amdgcn_s_setprio(0);

#define PH_MID()                                                              \
  __builtin_amdgcn_sched_barrier(0);                                          \
  __builtin_amdgcn_s_barrier();                                               \
  asm volatile("s_waitcnt lgkmcnt(0)" ::: "memory");                          \
  __builtin_amdgcn_sched_barrier(0);

#define PH_END()    __builtin_amdgcn_s_barrier();
#define PH_END_V6() asm volatile("s_waitcnt vmcnt(6)" ::: "memory"); \
                    __builtin_amdgcn_s_barrier();
#define PH_END_V8() asm volatile("s_waitcnt vmcnt(8)" ::: "memory"); \
                    __builtin_amdgcn_s_barrier();

// stage one 128x64 half-tile: 2 x gload16 per thread; advances stream ptr
#define STAGE(P, BUF, s, h)                                                   \
  gload16(P, &BUF[s][h][ldst]);                                               \
  gload16(P + 64 * D_, &BUF[s][h][4096 + ldst]);                              \
  P += 64;

__global__ __launch_bounds__(512, 2) void k_gemm1(
    const unsigned short* __restrict__ apad,
    const unsigned short* __restrict__ gub,
    const float* __restrict__ wpad,
    const int* __restrict__ meta,
    unsigned short* __restrict__ hpad) {
  int nst = meta[M_NST];
  int active = nst * NCT1;
  int bid = blockIdx.x;
  if (bid >= active) return;
  // bijective XCD chunk swizzle (m204): XCD x gets a contiguous item range;
  // items are (super-tile major, ct fastest) -> A-tile L2-resident per XCD,
  // and with balanced routing each XCD owns ~one expert's B panel.
  int x = bid & 7, idx = bid >> 3;
  int q = active >> 3, r = active & 7;
  int wgid = (x < r ? x * (q + 1) : r * (q + 1) + (x - r) * q) + idx;
  int st = wgid / NCT1;
  int ct = wgid - st * NCT1;
  int e = meta[M_STE + st], row0 = meta[M_STR + st], nv = meta[M_STV + st];

  __shared__ __attribute__((aligned(16))) __bf16 Abuf[2][2][128 * 64];
  __shared__ __attribute__((aligned(16))) __bf16 Bbuf[2][2][128 * 64];

  int tid = threadIdx.x;
  int lane = tid & 63;
  int wave = __builtin_amdgcn_readfirstlane(tid >> 6);
  int wm = wave >> 2, wn = wave & 3;        // 2(M) x 4(N) wave grid
  int l16 = lane & 15, qd = lane >> 4;

  // ---- staging source (pre-swizzled global address, m173/rule21) ----
  // dest chunk c = k*512+tid; row r = c>>3; stored logical chunk = (c^((c>>3)))&7
  int r0 = tid >> 3;                        // row within half for call 0
  int jl8 = (((tid >> 3) ^ tid) & 7) * 8;   // swizzled 16B-chunk column (elems)
  const __bf16* pa0 = (const __bf16*)apad + (size_t)(row0 + r0) * D_ + jl8;
  const __bf16* pa1 = pa0 + (size_t)128 * D_;
  const __bf16* pb0 = (const __bf16*)gub +
      ((size_t)e * TWOI_ + (size_t)ct * 128 + r0) * D_ + jl8;   // gate
  const __bf16* pb1 = pb0 + (size_t)I_ * D_;                    // up
  int ldst = wave * 512;                    // LDS dest elem offset (call0)

  // ---- ds_read addressing (XOR-swizzled): physical chunk = jc ^ (row&7) ----
  int swz0 = ((qd ^ (l16 & 7)) & 7) * 16;        // kk=0 (jc = qd)
  int swz1 = (((4 + qd) ^ (l16 & 7)) & 7) * 16;  // kk=1 (jc = 4+qd)
  int rbA = (wm * 64 + l16) * 128;               // byte row base in A half
  int cbB = (wn * 32 + l16) * 128;               // byte col base in B half

  floatx4 zero = {0.f, 0.f, 0.f, 0.f};
  floatx4 acc[4][4][2];                     // [quad mi2*2+ni2][mf][nf]
#pragma unroll
  for (int a = 0; a < 4; ++a)
#pragma unroll
    for (int b = 0; b < 4; ++b)
#pragma unroll
      for (int c = 0; c < 2; ++c) acc[a][b][c] = zero;

  // ---- prologue: prime 6 half-tiles (tiles 0 full, tile 1 A0/B0) ----
  STAGE(pa0, Abuf, 0, 0)
  STAGE(pb0, Bbuf, 0, 0)
  STAGE(pa1, Abuf, 0, 1)
  STAGE(pb1, Bbuf, 0, 1)
  STAGE(pa0, Abuf, 1, 0)
  STAGE(pb0, Bbuf, 1, 0)
  asm volatile("s_waitcnt vmcnt(8)" ::: "memory");  // A0(0),B0(0) landed
  __builtin_amdgcn_s_barrier();

  bf16x8 af[4][2], bq[2][2];
  for (int t = 0; t < 32; t += 2) {
#pragma unroll
    for (int u = 0; u < 2; ++u) {           // slot = u (t even)
      int tl = t + u;
      // ---- phase 0: quad (mi2=0, gate) ----
      RD_A(0, u)
      RD_B(0, u)
      if (tl + 1 < 32) { STAGE(pa1, Abuf, u ^ 1, 1) }
      PH_MID()
      MFMA_PH(0)
      PH_END_V6()                            // B1(tl) landed for phase 1
      // ---- phase 1: quad (mi2=0, up) ----
      RD_B(1, u)
      if (tl + 1 < 32) { STAGE(pb1, Bbuf, u ^ 1, 1) }
      PH_MID()
      MFMA_PH(1)
      PH_END()
      // ---- phase 2: quad (mi2=1, gate) ----
      RD_A(1, u)
      RD_B(0, u)
      if (tl + 2 < 32) { STAGE(pa0, Abuf, u, 0) }
      PH_MID()
      MFMA_PH(2)
      PH_END()
      // ---- phase 3: quad (mi2=1, up) ----
      RD_B(1, u)
      if (tl + 2 < 32) { STAGE(pb0, Bbuf, u, 0) }
      PH_MID()
      MFMA_PH(3)
      PH_END_V8()                            // A0(tl+1),B0(tl+1) landed
    }
  }

  // ---- epilogue: SwiGLU + routing weight -> hpad ----
#pragma unroll
  for (int mi2 = 0; mi2 < 2; ++mi2)
#pragma unroll
    for (int mf = 0; mf < 4; ++mf)
#pragma unroll
      for (int reg = 0; reg < 4; ++reg) {
        int lr = mi2 * 128 + wm * 64 + mf * 16 + qd * 4 + reg;
        if (lr < nv) {
          float wgt = wpad[row0 + lr];
          unsigned short* hrow = hpad + (size_t)(row0 + lr) * I_ +
                                 (size_t)ct * 128 + wn * 32 + l16;
#pragma unroll
          for (int nf = 0; nf < 2; ++nf) {
            float g = acc[mi2 * 2 + 0][mf][nf][reg];
            float uu = acc[mi2 * 2 + 1][mf][nf][reg];
            float s = g / (1.f + __expf(-g));
            hrow[nf * 16] = f2bf(s * uu * wgt);
          }
        }
      }
}

// -------------- GEMM2: out = h @ down^T, scatter rows (unchanged) --------------
__global__ __launch_bounds__(256) void k_gemm2(
    const unsigned short* __restrict__ hpad,
    const unsigned short* __restrict__ dnb,
    const int* __restrict__ meta,
    const int* __restrict__ perm,
    float* __restrict__ out) {
  int bid = blockIdx.x;
  int panel = bid / 128;            // 16 ct * 8 rt
  int rem = bid - panel * 128;
  int ct = rem >> 3;                // 0..15
  int rt = panel * 8 + (rem & 7);
  if (rt >= meta[M_NT]) return;
  int e = meta[M_RTE + rt], row0 = meta[M_RTR + rt], nv = meta[M_RTV + rt];

  __shared__ __attribute__((aligned(16))) __bf16 As[2][128 * 32];
  __shared__ __attribute__((aligned(16))) __bf16 Bs[2][128 * 32];

  int tid = threadIdx.x;
  int lane = tid & 63;
  int wave = __builtin_amdgcn_readfirstlane(tid >> 6);
  int wm = wave >> 1, wn = wave & 1;

  const __bf16* A = (const __bf16*)hpad + (size_t)row0 * I_;
  const __bf16* B = (const __bf16*)dnb + ((size_t)e * D_ + (size_t)ct * 128) * I_;

  int srow = lane >> 2;
  int skq = (lane & 3) * 8;

  floatx4 zero = {0.f, 0.f, 0.f, 0.f};
  floatx4 acc[4][4];
#pragma unroll
  for (int mi = 0; mi < 4; ++mi)
#pragma unroll
    for (int ni = 0; ni < 4; ++ni) acc[mi][ni] = zero;

  int quad8 = (lane >> 4) * 8;
  int l16 = lane & 15;

  for (int k0 = 0; k0 < I_; k0 += 64) {
#pragma unroll
    for (int p = 0; p < 2; ++p) {
      int kk = k0 + p * 32;
      gload16(A + (size_t)(wave * 16 + srow) * I_ + kk + skq, &As[p][(wave * 16) * 32]);
      gload16(A + (size_t)(64 + wave * 16 + srow) * I_ + kk + skq, &As[p][(64 + wave * 16) * 32]);
      gload16(B + (size_t)(wave * 16 + srow) * I_ + kk + skq, &Bs[p][(wave * 16) * 32]);
      gload16(B + (size_t)(64 + wave * 16 + srow) * I_ + kk + skq, &Bs[p][(64 + wave * 16) * 32]);
    }
    __syncthreads();
#pragma unroll
    for (int p = 0; p < 2; ++p) {
      bf16x8 af[4], bfr[4];
#pragma unroll
      for (int mi = 0; mi < 4; ++mi)
        af[mi] = *(const bf16x8*)&As[p][(wm * 64 + mi * 16 + l16) * 32 + quad8];
#pragma unroll
      for (int ni = 0; ni < 4; ++ni)
        bfr[ni] = *(const bf16x8*)&Bs[p][(wn * 64 + ni * 16 + l16) * 32 + quad8];
#pragma unroll
      for (int mi = 0; mi < 4; ++mi)
#pragma unroll
        for (int ni = 0; ni < 4; ++ni)
          acc[mi][ni] = __builtin_amdgcn_mfma_f32_16x16x32_bf16(af[mi], bfr[ni], acc[mi][ni], 0, 0, 0);
    }
    __syncthreads();
  }

  int quad = lane >> 4;
#pragma unroll
  for (int mi = 0; mi < 4; ++mi)
#pragma unroll
    for (int reg = 0; reg < 4; ++reg) {
      int r = wm * 64 + mi * 16 + quad * 4 + reg;
      if (r < nv) {
        int t = perm[row0 + r];
        float* orow = out + (size_t)t * D_ + (size_t)ct * 128 + wn * 64;
#pragma unroll
        for (int ni = 0; ni < 4; ++ni)
          orow[ni * 16 + l16] = acc[mi][ni][reg];
      }
    }
}

// -------------- fallback (tiny ws): correct but slow --------------
__global__ __launch_bounds__(256) void k_naive(
    const float* __restrict__ tokens, const int* __restrict__ ids,
    const float* __restrict__ w, const float* __restrict__ gu,
    const float* __restrict__ dn, float* __restrict__ out) {
  __shared__ float tok[D_];
  __shared__ float h[I_];
  int t = blockIdx.x;
  int e = ids[t];
  float wgt = w[t];
  for (int i = threadIdx.x; i < D_; i += 256) tok[i] = tokens[(size_t)t * D_ + i];
  __syncthreads();
  for (int j = threadIdx.x; j < I_; j += 256) {
    const float* wg = gu + ((size_t)e * TWOI_ + j) * D_;
    const float* wu = wg + (size_t)I_ * D_;
    float g = 0.f, u = 0.f;
    for (int k = 0; k < D_; ++k) { g += tok[k] * wg[k]; u += tok[k] * wu[k]; }
    h[j] = g / (1.f + __expf(-g)) * u * wgt;
  }
  __syncthreads();
  for (int d = threadIdx.x; d < D_; d += 256) {
    const float* wd = dn + ((size_t)e * D_ + d) * I_;
    float acc = 0.f;
    for (int k = 0; k < I_; ++k) acc += h[k] * wd[k];
    out[(size_t)t * D_ + d] = acc;
  }
}

extern "C" void kernel_launch(void* const* d_in, const int* in_sizes, int n_in,
                              void* d_out, int out_size, void* d_ws, size_t ws_size,
                              hipStream_t stream) {
  const float* tokens = (const float*)d_in[0];
  const int*   ids    = (const int*)d_in[1];
  const float* wts    = (const float*)d_in[2];
  const float* gu     = (const float*)d_in[3];
  const float* dn     = (const float*)d_in[4];
  float* out = (float*)d_out;

  if (ws_size < (size_t)WS_NEED) {
    k_naive<<<N_, 256, 0, stream>>>(tokens, ids, wts, gu, dn, out);
    return;
  }

  char* ws = (char*)d_ws;
  int* meta = (int*)ws;
  int* perm = (int*)(ws + OFF_PERM);
  float* wpad = (float*)(ws + OFF_WPAD);
  unsigned short* apad = (unsigned short*)(ws + OFF_APAD);
  unsigned short* hpad = (unsigned short*)(ws + OFF_HPAD);
  unsigned short* gub  = (unsigned short*)(ws + OFF_GU);
  unsigned short* dnb  = (unsigned short*)(ws + OFF_DN);

  hipMemsetAsync(meta, 0, 64, stream);                 // cnt + cur
  hipMemsetAsync(perm, 0xFF, MPAD * 4, stream);        // perm = -1
  k_hist<<<N_ / 256, 256, 0, stream>>>(ids, meta);
  k_meta<<<1, 1, 0, stream>>>(meta);
  k_scatter<<<N_ / 256, 256, 0, stream>>>(ids, wts, meta, perm, wpad);
  k_gather<<<MPAD, 256, 0, stream>>>(tokens, perm, apad);
  int ngu8 = E_ * TWOI_ * D_ / 8;
  int ndn8 = E_ * D_ * I_ / 8;
  k_cvt<<<(ngu8 + 255) / 256, 256, 0, stream>>>(gu, gub, ngu8);
  k_cvt<<<(ndn8 + 255) / 256, 256, 0, stream>>>(dn, dnb, ndn8);
  k_gemm1<<<NCT1 * MAXST, 512, 0, stream>>>(apad, gub, wpad, meta, hpad);
  k_gemm2<<<9 * 128, 256, 0, stream>>>(hpad, dnb, meta, perm, out);
}